// Round 4
// baseline (934.659 us; speedup 1.0000x reference)
//
#include <hip/hip_runtime.h>

#define F_IN 512
#define HID  16
#define NCLS 7
#define BSH  7            // log2(nodes per bucket)
#define NPB  128          // nodes per bucket
#define MAXBKT 1024       // supports n <= 131072
#define GRID_P 512        // blocks for hist/partition passes

// ---------------- bucketed edge partition ----------------

__global__ void k_zero(int* __restrict__ p, int m) {
    int i = blockIdx.x * blockDim.x + threadIdx.x;
    if (i < m) p[i] = 0;
}

// bucket histogram: LDS-aggregate, flush to line-padded global counters
__global__ void k_bhist(const int* __restrict__ dst, int* __restrict__ bcnt,
                        int E, int nbkt, int chunk) {
    __shared__ int h[MAXBKT];
    for (int i = threadIdx.x; i < nbkt; i += blockDim.x) h[i] = 0;
    __syncthreads();
    int base = blockIdx.x * chunk;
    int end = min(base + chunk, E);
    for (int e = base + threadIdx.x; e < end; e += blockDim.x)
        atomicAdd(&h[((unsigned)dst[e]) >> BSH], 1);
    __syncthreads();
    for (int i = threadIdx.x; i < nbkt; i += blockDim.x)
        if (h[i]) atomicAdd(&bcnt[i * 16], h[i]);   // stride-16: one counter per line
}

// exclusive scan of nbkt (<=1024) padded counts -> dense bptr + padded bcur
__global__ void k_bscan(const int* __restrict__ bcnt, int* __restrict__ bptr,
                        int* __restrict__ bcur, int nbkt) {
    __shared__ int s[1024];
    int tid = threadIdx.x;
    int v = (tid < nbkt) ? bcnt[tid * 16] : 0;
    s[tid] = v;
    __syncthreads();
    for (int off = 1; off < 1024; off <<= 1) {
        int t = (tid >= off) ? s[tid - off] : 0;
        __syncthreads();
        if (tid >= off) s[tid] += t;
        __syncthreads();
    }
    if (tid < nbkt) {
        int e = s[tid] - v;
        bptr[tid] = e;
        bcur[tid * 16] = e;
    }
}

// partition edges into bucket segments as packed (src<<BSH)|local_dst
__global__ void k_part(const int* __restrict__ ei, int* __restrict__ bcur,
                       unsigned* __restrict__ pairs, int E, int nbkt, int chunk) {
    __shared__ int h[MAXBKT];
    __shared__ int cur[MAXBKT];
    int tid = threadIdx.x;
    for (int i = tid; i < nbkt; i += blockDim.x) h[i] = 0;
    __syncthreads();
    int base = blockIdx.x * chunk;
    int end = min(base + chunk, E);
    for (int e = base + tid; e < end; e += blockDim.x)
        atomicAdd(&h[((unsigned)ei[E + e]) >> BSH], 1);
    __syncthreads();
    for (int i = tid; i < nbkt; i += blockDim.x) {
        int c = h[i];
        cur[i] = c ? atomicAdd(&bcur[i * 16], c) : 0;
    }
    __syncthreads();
    for (int e = base + tid; e < end; e += blockDim.x) {
        int d = ei[E + e];
        int b = ((unsigned)d) >> BSH;
        int pos = atomicAdd(&cur[b], 1);
        pairs[pos] = (((unsigned)ei[e]) << BSH) | (unsigned)(d & (NPB - 1));
    }
}

// per-bucket degree -> dinv (single pass over pairs, LDS hist)
__global__ __launch_bounds__(256) void k_deg(const unsigned* __restrict__ pairs,
                                             const int* __restrict__ bptr,
                                             float* __restrict__ dinv,
                                             int n, int E, int nbkt) {
    int b = blockIdx.x, tid = threadIdx.x;
    __shared__ int h[NPB];
    if (tid < NPB) h[tid] = 0;
    __syncthreads();
    int pb = bptr[b];
    int pe = (b + 1 < nbkt) ? bptr[b + 1] : E;
    for (int p = pb + tid; p < pe; p += 256)
        atomicAdd(&h[pairs[p] & (NPB - 1)], 1);
    __syncthreads();
    if (tid < NPB) {
        int node = (b << BSH) + tid;
        if (node < n) dinv[node] = rsqrtf((float)(h[tid] + 1));  // +1 self loop
    }
}

// ---------------- layer math ----------------

// h1 = x @ W1. 1 thread/node; k unrolled by 32 so each lane consumes whole
// 128B lines; W1 accesses wave-uniform -> scalar loads.
__global__ __launch_bounds__(256) void k_gemm1(const float* __restrict__ x,
                                               const float* __restrict__ W1,
                                               float* __restrict__ h1, int n) {
    int node = blockIdx.x * blockDim.x + threadIdx.x;
    if (node >= n) return;
    float acc[HID];
#pragma unroll
    for (int j = 0; j < HID; j++) acc[j] = 0.f;
    const float* xr = x + (size_t)node * F_IN;
    for (int k0 = 0; k0 < F_IN; k0 += 32) {
        float4 xv[8];
        const float4* xp = (const float4*)(xr + k0);
#pragma unroll
        for (int u = 0; u < 8; u++) xv[u] = xp[u];
#pragma unroll
        for (int u = 0; u < 8; u++) {
#pragma unroll
            for (int kk = 0; kk < 4; kk++) {
                float xk = ((const float*)&xv[u])[kk];
                const float* wr = W1 + (size_t)(k0 + u * 4 + kk) * HID;
#pragma unroll
                for (int j = 0; j < HID; j++) acc[j] = fmaf(xk, wr[j], acc[j]);
            }
        }
    }
    float4* o4 = (float4*)(h1 + (size_t)node * HID);
#pragma unroll
    for (int q = 0; q < 4; q++)
        o4[q] = float4{acc[q * 4 + 0], acc[q * 4 + 1], acc[q * 4 + 2], acc[q * 4 + 3]};
}

// Layer-1 aggregation, LDS-accumulated per bucket, fused relu + z@W2 -> t.
// tile stride 17 (coprime with 32 banks) -> random-row ds_add ~2-way = free.
__global__ __launch_bounds__(256) void k_agg1(
    const unsigned* __restrict__ pairs, const int* __restrict__ bptr,
    const float* __restrict__ dinv, const float* __restrict__ h1,
    const float* __restrict__ b1, const float* __restrict__ W2,
    float* __restrict__ t, int n, int E, int nbkt) {
    int b = blockIdx.x, tid = threadIdx.x;
    __shared__ float tile[NPB * 17];
    __shared__ float dinvL[NPB];
    for (int i = tid; i < NPB * 17; i += 256) tile[i] = 0.f;
    if (tid < NPB) {
        int node = (b << BSH) + tid;
        dinvL[tid] = (node < n) ? dinv[node] : 0.f;
    }
    __syncthreads();
    int pb = bptr[b];
    int pe = (b + 1 < nbkt) ? bptr[b + 1] : E;
    for (int p = pb + tid; p < pe; p += 256) {
        unsigned v = pairs[p];
        int ld = v & (NPB - 1);
        int src = v >> BSH;
        float nm = dinv[src] * dinvL[ld];
        const float4* hr = (const float4*)(h1 + (size_t)src * HID);
        float4 a = hr[0], c = hr[1], d = hr[2], e4 = hr[3];
        float* row = &tile[ld * 17];
        atomicAdd(&row[0],  nm * a.x);  atomicAdd(&row[1],  nm * a.y);
        atomicAdd(&row[2],  nm * a.z);  atomicAdd(&row[3],  nm * a.w);
        atomicAdd(&row[4],  nm * c.x);  atomicAdd(&row[5],  nm * c.y);
        atomicAdd(&row[6],  nm * c.z);  atomicAdd(&row[7],  nm * c.w);
        atomicAdd(&row[8],  nm * d.x);  atomicAdd(&row[9],  nm * d.y);
        atomicAdd(&row[10], nm * d.z);  atomicAdd(&row[11], nm * d.w);
        atomicAdd(&row[12], nm * e4.x); atomicAdd(&row[13], nm * e4.y);
        atomicAdd(&row[14], nm * e4.z); atomicAdd(&row[15], nm * e4.w);
    }
    __syncthreads();
    if (tid < NPB) {
        int node = (b << BSH) + tid;
        if (node < n) {
            float dc = dinvL[tid], d2 = dc * dc;
            const float4* hs = (const float4*)(h1 + (size_t)node * HID);
            const float* row = &tile[tid * 17];
            float z[HID];
#pragma unroll
            for (int q = 0; q < 4; q++) {
                float4 hv = hs[q];
                z[q * 4 + 0] = fmaxf(fmaf(d2, hv.x, row[q * 4 + 0]) + b1[q * 4 + 0], 0.f);
                z[q * 4 + 1] = fmaxf(fmaf(d2, hv.y, row[q * 4 + 1]) + b1[q * 4 + 1], 0.f);
                z[q * 4 + 2] = fmaxf(fmaf(d2, hv.z, row[q * 4 + 2]) + b1[q * 4 + 2], 0.f);
                z[q * 4 + 3] = fmaxf(fmaf(d2, hv.w, row[q * 4 + 3]) + b1[q * 4 + 3], 0.f);
            }
            float tv[8];
#pragma unroll
            for (int c = 0; c < NCLS; c++) {
                float s = 0.f;
#pragma unroll
                for (int k = 0; k < HID; k++) s = fmaf(z[k], W2[k * NCLS + c], s);
                tv[c] = s;
            }
            tv[7] = 0.f;
            float4* o4 = (float4*)(t + (size_t)node * 8);
            o4[0] = float4{tv[0], tv[1], tv[2], tv[3]};
            o4[1] = float4{tv[4], tv[5], tv[6], tv[7]};
        }
    }
}

// Layer-2 aggregation: LDS tile stride 9 (coprime 32), epilogue writes all of out.
__global__ __launch_bounds__(256) void k_agg2(
    const unsigned* __restrict__ pairs, const int* __restrict__ bptr,
    const float* __restrict__ dinv, const float* __restrict__ t,
    const float* __restrict__ b2, float* __restrict__ out, int n, int E, int nbkt) {
    int b = blockIdx.x, tid = threadIdx.x;
    __shared__ float tile[NPB * 9];
    __shared__ float dinvL[NPB];
    for (int i = tid; i < NPB * 9; i += 256) tile[i] = 0.f;
    if (tid < NPB) {
        int node = (b << BSH) + tid;
        dinvL[tid] = (node < n) ? dinv[node] : 0.f;
    }
    __syncthreads();
    int pb = bptr[b];
    int pe = (b + 1 < nbkt) ? bptr[b + 1] : E;
    for (int p = pb + tid; p < pe; p += 256) {
        unsigned v = pairs[p];
        int ld = v & (NPB - 1);
        int src = v >> BSH;
        float nm = dinv[src] * dinvL[ld];
        const float4* tr = (const float4*)(t + (size_t)src * 8);
        float4 a = tr[0], c = tr[1];
        float* row = &tile[ld * 9];
        atomicAdd(&row[0], nm * a.x); atomicAdd(&row[1], nm * a.y);
        atomicAdd(&row[2], nm * a.z); atomicAdd(&row[3], nm * a.w);
        atomicAdd(&row[4], nm * c.x); atomicAdd(&row[5], nm * c.y);
        atomicAdd(&row[6], nm * c.z);
    }
    __syncthreads();
    if (tid < NPB) {
        int node = (b << BSH) + tid;
        if (node < n) {
            float dc = dinvL[tid], d2 = dc * dc;
            const float4* ts4 = (const float4*)(t + (size_t)node * 8);
            float4 s0 = ts4[0], s1 = ts4[1];
            float self[NCLS] = {s0.x, s0.y, s0.z, s0.w, s1.x, s1.y, s1.z};
            const float* row = &tile[tid * 9];
            float* o = out + (size_t)node * NCLS;
#pragma unroll
            for (int c = 0; c < NCLS; c++)
                o[c] = fmaf(d2, self[c], row[c]) + b2[c];
        }
    }
}

extern "C" void kernel_launch(void* const* d_in, const int* in_sizes, int n_in,
                              void* d_out, int out_size, void* d_ws, size_t ws_size,
                              hipStream_t stream) {
    const float* x  = (const float*)d_in[0];
    const int*   ei = (const int*)d_in[1];
    const float* W1 = (const float*)d_in[2];
    const float* b1 = (const float*)d_in[3];
    const float* W2 = (const float*)d_in[4];
    const float* b2 = (const float*)d_in[5];
    float* out = (float*)d_out;

    int n = in_sizes[0] / F_IN;   // 100000
    int E = in_sizes[1] / 2;      // 3200000
    int nbkt = (n + NPB - 1) >> BSH;  // 782

    float* ws = (float*)d_ws;
    float* dinv     = ws;                              // n
    unsigned* pairs = (unsigned*)(ws + n);             // E
    float* h1       = ws + n + (size_t)E;              // 16n
    float* t        = h1 + 16 * (size_t)n;             // 8n (stride-8 padded)
    int*   bcnt     = (int*)(t + 8 * (size_t)n);       // 1024*16 (line-padded)
    int*   bptr     = bcnt + 1024 * 16;                // 1024 dense
    int*   bcur     = bptr + 1024;                     // 1024*16 (line-padded)

    const int B = 256;
    int chunk = (E + GRID_P - 1) / GRID_P;

    k_zero<<<dim3((1024 * 16 + B - 1) / B), dim3(B), 0, stream>>>(bcnt, 1024 * 16);
    k_bhist<<<dim3(GRID_P), dim3(B), 0, stream>>>(ei + E, bcnt, E, nbkt, chunk);
    k_bscan<<<dim3(1), dim3(1024), 0, stream>>>(bcnt, bptr, bcur, nbkt);
    k_part<<<dim3(GRID_P), dim3(B), 0, stream>>>(ei, bcur, pairs, E, nbkt, chunk);
    k_deg<<<dim3(nbkt), dim3(B), 0, stream>>>(pairs, bptr, dinv, n, E, nbkt);
    k_gemm1<<<dim3((n + B - 1) / B), dim3(B), 0, stream>>>(x, W1, h1, n);
    k_agg1<<<dim3(nbkt), dim3(B), 0, stream>>>(pairs, bptr, dinv, h1, b1, W2, t, n, E, nbkt);
    k_agg2<<<dim3(nbkt), dim3(B), 0, stream>>>(pairs, bptr, dinv, t, b2, out, n, E, nbkt);
}

// Round 5
// 584.819 us; speedup vs baseline: 1.5982x; 1.5982x over previous
//
#include <hip/hip_runtime.h>

#define F_IN 512
#define HID  16
#define NCLS 7
#define BSH  7            // log2(nodes per bucket)
#define NPB  128          // nodes per bucket
#define MAXBKT 1024       // supports n <= 131072
#define GRID_P 512        // blocks for hist/partition passes

// ---------------- bucketed CSR build (Round-3 proven) ----------------

__global__ void k_zero(int* __restrict__ p, int m) {
    int i = blockIdx.x * blockDim.x + threadIdx.x;
    if (i < m) p[i] = 0;
}

__global__ void k_bhist(const int* __restrict__ dst, int* __restrict__ bcnt,
                        int E, int nbkt, int chunk) {
    __shared__ int h[MAXBKT];
    for (int i = threadIdx.x; i < nbkt; i += blockDim.x) h[i] = 0;
    __syncthreads();
    int base = blockIdx.x * chunk;
    int end = min(base + chunk, E);
    for (int e = base + threadIdx.x; e < end; e += blockDim.x)
        atomicAdd(&h[((unsigned)dst[e]) >> BSH], 1);
    __syncthreads();
    for (int i = threadIdx.x; i < nbkt; i += blockDim.x)
        if (h[i]) atomicAdd(&bcnt[i * 16], h[i]);   // stride-16: one counter per line
}

__global__ void k_bscan(const int* __restrict__ bcnt, int* __restrict__ bptr,
                        int* __restrict__ bcur, int nbkt) {
    __shared__ int s[1024];
    int tid = threadIdx.x;
    int v = (tid < nbkt) ? bcnt[tid * 16] : 0;
    s[tid] = v;
    __syncthreads();
    for (int off = 1; off < 1024; off <<= 1) {
        int t = (tid >= off) ? s[tid - off] : 0;
        __syncthreads();
        if (tid >= off) s[tid] += t;
        __syncthreads();
    }
    if (tid < nbkt) {
        int e = s[tid] - v;
        bptr[tid] = e;
        bcur[tid * 16] = e;
    }
}

__global__ void k_part(const int* __restrict__ ei, int* __restrict__ bcur,
                       unsigned* __restrict__ pairs, int E, int nbkt, int chunk) {
    __shared__ int h[MAXBKT];
    __shared__ int cur[MAXBKT];
    int tid = threadIdx.x;
    for (int i = tid; i < nbkt; i += blockDim.x) h[i] = 0;
    __syncthreads();
    int base = blockIdx.x * chunk;
    int end = min(base + chunk, E);
    for (int e = base + tid; e < end; e += blockDim.x)
        atomicAdd(&h[((unsigned)ei[E + e]) >> BSH], 1);
    __syncthreads();
    for (int i = tid; i < nbkt; i += blockDim.x) {
        int c = h[i];
        cur[i] = c ? atomicAdd(&bcur[i * 16], c) : 0;
    }
    __syncthreads();
    for (int e = base + tid; e < end; e += blockDim.x) {
        int d = ei[E + e];
        int b = ((unsigned)d) >> BSH;
        int pos = atomicAdd(&cur[b], 1);
        pairs[pos] = (((unsigned)ei[e]) << BSH) | (unsigned)(d & (NPB - 1));
    }
}

// per-bucket: LDS hist + scan -> row_ptr, dinv; LDS-cursor fill of srcarr
__global__ __launch_bounds__(NPB) void k_bfill(
    const unsigned* __restrict__ pairs, const int* __restrict__ bptr,
    int* __restrict__ row_ptr, int* __restrict__ srcarr,
    float* __restrict__ dinv, int n, int E, int nbkt) {
    int b = blockIdx.x, tid = threadIdx.x;
    int pb = bptr[b];
    int pe = (b + 1 < nbkt) ? bptr[b + 1] : E;
    __shared__ int h[NPB];
    __shared__ int s[NPB];
    h[tid] = 0;
    __syncthreads();
    for (int p = pb + tid; p < pe; p += NPB)
        atomicAdd(&h[pairs[p] & (NPB - 1)], 1);
    __syncthreads();
    int cnt = h[tid];
    s[tid] = cnt;
    __syncthreads();
    for (int off = 1; off < NPB; off <<= 1) {
        int t = (tid >= off) ? s[tid - off] : 0;
        __syncthreads();
        if (tid >= off) s[tid] += t;
        __syncthreads();
    }
    int excl = s[tid] - cnt;
    int node = (b << BSH) + tid;
    if (node < n) {
        row_ptr[node] = pb + excl;
        dinv[node] = rsqrtf((float)(cnt + 1));  // +1 self loop
    }
    h[tid] = pb + excl;  // reuse as cursor
    __syncthreads();
    for (int p = pb + tid; p < pe; p += NPB) {
        unsigned v = pairs[p];
        int pos = atomicAdd(&h[v & (NPB - 1)], 1);
        srcarr[pos] = (int)(v >> BSH);
    }
    if (b == 0 && tid == 0) row_ptr[n] = E;
}

// ---------------- layer math ----------------

// h1 = x @ W1. 1 thread/node; k unrolled by 32 so each lane consumes whole
// 128B lines; W1 accesses wave-uniform -> scalar loads.
__global__ __launch_bounds__(256) void k_gemm1(const float* __restrict__ x,
                                               const float* __restrict__ W1,
                                               float* __restrict__ h1, int n) {
    int node = blockIdx.x * blockDim.x + threadIdx.x;
    if (node >= n) return;
    float acc[HID];
#pragma unroll
    for (int j = 0; j < HID; j++) acc[j] = 0.f;
    const float* xr = x + (size_t)node * F_IN;
    for (int k0 = 0; k0 < F_IN; k0 += 32) {
        float4 xv[8];
        const float4* xp = (const float4*)(xr + k0);
#pragma unroll
        for (int u = 0; u < 8; u++) xv[u] = xp[u];
#pragma unroll
        for (int u = 0; u < 8; u++) {
#pragma unroll
            for (int kk = 0; kk < 4; kk++) {
                float xk = ((const float*)&xv[u])[kk];
                const float* wr = W1 + (size_t)(k0 + u * 4 + kk) * HID;
#pragma unroll
                for (int j = 0; j < HID; j++) acc[j] = fmaf(xk, wr[j], acc[j]);
            }
        }
    }
    float4* o4 = (float4*)(h1 + (size_t)node * HID);
#pragma unroll
    for (int q = 0; q < 4; q++)
        o4[q] = float4{acc[q * 4 + 0], acc[q * 4 + 1], acc[q * 4 + 2], acc[q * 4 + 3]};
}

// Gather layer 1: 4 lanes/node, lane q takes edges eb+q, eb+q+4, ... and
// accumulates the FULL 16-float row (4x float4 loads/edge, unroll x2 -> ~10
// loads in flight). Width-4 shfl_xor butterfly, then fused relu + z@W2 -> t.
__global__ __launch_bounds__(256) void k_gather1(
    const int* __restrict__ row_ptr, const int* __restrict__ srcarr,
    const float* __restrict__ dinv, const float* __restrict__ h1,
    const float* __restrict__ b1, const float* __restrict__ W2,
    float* __restrict__ t, int n) {
    int g = blockIdx.x * blockDim.x + threadIdx.x;
    int node = g >> 2, q = g & 3;
    if (node >= n) return;
    int eb = row_ptr[node], ee = row_ptr[node + 1];
    float dc = dinv[node];
    const float4* h4 = (const float4*)h1;
    float4 a0 = {0,0,0,0}, a1 = {0,0,0,0}, a2 = {0,0,0,0}, a3 = {0,0,0,0};
    int e = eb + q;
    for (; e + 4 < ee; e += 8) {
        int r0 = srcarr[e], r1 = srcarr[e + 4];
        float nm0 = dinv[r0] * dc, nm1 = dinv[r1] * dc;
        float4 u0 = h4[(size_t)r0 * 4 + 0], u1 = h4[(size_t)r0 * 4 + 1];
        float4 u2 = h4[(size_t)r0 * 4 + 2], u3 = h4[(size_t)r0 * 4 + 3];
        float4 v0 = h4[(size_t)r1 * 4 + 0], v1 = h4[(size_t)r1 * 4 + 1];
        float4 v2 = h4[(size_t)r1 * 4 + 2], v3 = h4[(size_t)r1 * 4 + 3];
        a0.x = fmaf(nm0, u0.x, a0.x); a0.y = fmaf(nm0, u0.y, a0.y);
        a0.z = fmaf(nm0, u0.z, a0.z); a0.w = fmaf(nm0, u0.w, a0.w);
        a1.x = fmaf(nm0, u1.x, a1.x); a1.y = fmaf(nm0, u1.y, a1.y);
        a1.z = fmaf(nm0, u1.z, a1.z); a1.w = fmaf(nm0, u1.w, a1.w);
        a2.x = fmaf(nm0, u2.x, a2.x); a2.y = fmaf(nm0, u2.y, a2.y);
        a2.z = fmaf(nm0, u2.z, a2.z); a2.w = fmaf(nm0, u2.w, a2.w);
        a3.x = fmaf(nm0, u3.x, a3.x); a3.y = fmaf(nm0, u3.y, a3.y);
        a3.z = fmaf(nm0, u3.z, a3.z); a3.w = fmaf(nm0, u3.w, a3.w);
        a0.x = fmaf(nm1, v0.x, a0.x); a0.y = fmaf(nm1, v0.y, a0.y);
        a0.z = fmaf(nm1, v0.z, a0.z); a0.w = fmaf(nm1, v0.w, a0.w);
        a1.x = fmaf(nm1, v1.x, a1.x); a1.y = fmaf(nm1, v1.y, a1.y);
        a1.z = fmaf(nm1, v1.z, a1.z); a1.w = fmaf(nm1, v1.w, a1.w);
        a2.x = fmaf(nm1, v2.x, a2.x); a2.y = fmaf(nm1, v2.y, a2.y);
        a2.z = fmaf(nm1, v2.z, a2.z); a2.w = fmaf(nm1, v2.w, a2.w);
        a3.x = fmaf(nm1, v3.x, a3.x); a3.y = fmaf(nm1, v3.y, a3.y);
        a3.z = fmaf(nm1, v3.z, a3.z); a3.w = fmaf(nm1, v3.w, a3.w);
    }
    if (e < ee) {
        int r0 = srcarr[e];
        float nm0 = dinv[r0] * dc;
        float4 u0 = h4[(size_t)r0 * 4 + 0], u1 = h4[(size_t)r0 * 4 + 1];
        float4 u2 = h4[(size_t)r0 * 4 + 2], u3 = h4[(size_t)r0 * 4 + 3];
        a0.x = fmaf(nm0, u0.x, a0.x); a0.y = fmaf(nm0, u0.y, a0.y);
        a0.z = fmaf(nm0, u0.z, a0.z); a0.w = fmaf(nm0, u0.w, a0.w);
        a1.x = fmaf(nm0, u1.x, a1.x); a1.y = fmaf(nm0, u1.y, a1.y);
        a1.z = fmaf(nm0, u1.z, a1.z); a1.w = fmaf(nm0, u1.w, a1.w);
        a2.x = fmaf(nm0, u2.x, a2.x); a2.y = fmaf(nm0, u2.y, a2.y);
        a2.z = fmaf(nm0, u2.z, a2.z); a2.w = fmaf(nm0, u2.w, a2.w);
        a3.x = fmaf(nm0, u3.x, a3.x); a3.y = fmaf(nm0, u3.y, a3.y);
        a3.z = fmaf(nm0, u3.z, a3.z); a3.w = fmaf(nm0, u3.w, a3.w);
    }
    // sum across the 4 lanes of the group (all lanes end with the full row)
#pragma unroll
    for (int m = 1; m < 4; m <<= 1) {
        a0.x += __shfl_xor(a0.x, m, 4); a0.y += __shfl_xor(a0.y, m, 4);
        a0.z += __shfl_xor(a0.z, m, 4); a0.w += __shfl_xor(a0.w, m, 4);
        a1.x += __shfl_xor(a1.x, m, 4); a1.y += __shfl_xor(a1.y, m, 4);
        a1.z += __shfl_xor(a1.z, m, 4); a1.w += __shfl_xor(a1.w, m, 4);
        a2.x += __shfl_xor(a2.x, m, 4); a2.y += __shfl_xor(a2.y, m, 4);
        a2.z += __shfl_xor(a2.z, m, 4); a2.w += __shfl_xor(a2.w, m, 4);
        a3.x += __shfl_xor(a3.x, m, 4); a3.y += __shfl_xor(a3.y, m, 4);
        a3.z += __shfl_xor(a3.z, m, 4); a3.w += __shfl_xor(a3.w, m, 4);
    }
    float acc[HID] = {a0.x, a0.y, a0.z, a0.w, a1.x, a1.y, a1.z, a1.w,
                      a2.x, a2.y, a2.z, a2.w, a3.x, a3.y, a3.z, a3.w};
    // self loop + bias + relu (redundant across the 4 lanes; L1-hit loads)
    float d2 = dc * dc;
    const float4* hs = (const float4*)(h1 + (size_t)node * HID);
    float z[HID];
#pragma unroll
    for (int qq = 0; qq < 4; qq++) {
        float4 hv = hs[qq];
        z[qq * 4 + 0] = fmaxf(fmaf(d2, hv.x, acc[qq * 4 + 0]) + b1[qq * 4 + 0], 0.f);
        z[qq * 4 + 1] = fmaxf(fmaf(d2, hv.y, acc[qq * 4 + 1]) + b1[qq * 4 + 1], 0.f);
        z[qq * 4 + 2] = fmaxf(fmaf(d2, hv.z, acc[qq * 4 + 2]) + b1[qq * 4 + 2], 0.f);
        z[qq * 4 + 3] = fmaxf(fmaf(d2, hv.w, acc[qq * 4 + 3]) + b1[qq * 4 + 3], 0.f);
    }
    // lane q -> t columns 2q, 2q+1 (col 7 = pad = 0)
    int j0 = q * 2, j1 = q * 2 + 1;
    float t0 = 0.f, t1 = 0.f;
#pragma unroll
    for (int k = 0; k < HID; k++) {
        t0 = fmaf(z[k], W2[k * NCLS + j0], t0);
        if (j1 < NCLS) t1 = fmaf(z[k], W2[k * NCLS + j1], t1);
    }
    if (j1 >= NCLS) t1 = 0.f;
    ((float2*)t)[(size_t)node * 4 + q] = float2{t0, t1};
}

// Gather layer 2: same structure, 8-float rows of t. Lane q writes out cols
// {2q, 2q+1} (col 7 skipped) -> every output element written exactly once.
__global__ __launch_bounds__(256) void k_gather2(
    const int* __restrict__ row_ptr, const int* __restrict__ srcarr,
    const float* __restrict__ dinv, const float* __restrict__ t,
    const float* __restrict__ b2, float* __restrict__ out, int n) {
    int g = blockIdx.x * blockDim.x + threadIdx.x;
    int node = g >> 2, q = g & 3;
    if (node >= n) return;
    int eb = row_ptr[node], ee = row_ptr[node + 1];
    float dc = dinv[node];
    const float4* t4 = (const float4*)t;
    float4 a0 = {0,0,0,0}, a1 = {0,0,0,0};
    int e = eb + q;
    for (; e + 4 < ee; e += 8) {
        int r0 = srcarr[e], r1 = srcarr[e + 4];
        float nm0 = dinv[r0] * dc, nm1 = dinv[r1] * dc;
        float4 u0 = t4[(size_t)r0 * 2 + 0], u1 = t4[(size_t)r0 * 2 + 1];
        float4 v0 = t4[(size_t)r1 * 2 + 0], v1 = t4[(size_t)r1 * 2 + 1];
        a0.x = fmaf(nm0, u0.x, a0.x); a0.y = fmaf(nm0, u0.y, a0.y);
        a0.z = fmaf(nm0, u0.z, a0.z); a0.w = fmaf(nm0, u0.w, a0.w);
        a1.x = fmaf(nm0, u1.x, a1.x); a1.y = fmaf(nm0, u1.y, a1.y);
        a1.z = fmaf(nm0, u1.z, a1.z); a1.w = fmaf(nm0, u1.w, a1.w);
        a0.x = fmaf(nm1, v0.x, a0.x); a0.y = fmaf(nm1, v0.y, a0.y);
        a0.z = fmaf(nm1, v0.z, a0.z); a0.w = fmaf(nm1, v0.w, a0.w);
        a1.x = fmaf(nm1, v1.x, a1.x); a1.y = fmaf(nm1, v1.y, a1.y);
        a1.z = fmaf(nm1, v1.z, a1.z); a1.w = fmaf(nm1, v1.w, a1.w);
    }
    if (e < ee) {
        int r0 = srcarr[e];
        float nm0 = dinv[r0] * dc;
        float4 u0 = t4[(size_t)r0 * 2 + 0], u1 = t4[(size_t)r0 * 2 + 1];
        a0.x = fmaf(nm0, u0.x, a0.x); a0.y = fmaf(nm0, u0.y, a0.y);
        a0.z = fmaf(nm0, u0.z, a0.z); a0.w = fmaf(nm0, u0.w, a0.w);
        a1.x = fmaf(nm0, u1.x, a1.x); a1.y = fmaf(nm0, u1.y, a1.y);
        a1.z = fmaf(nm0, u1.z, a1.z); a1.w = fmaf(nm0, u1.w, a1.w);
    }
#pragma unroll
    for (int m = 1; m < 4; m <<= 1) {
        a0.x += __shfl_xor(a0.x, m, 4); a0.y += __shfl_xor(a0.y, m, 4);
        a0.z += __shfl_xor(a0.z, m, 4); a0.w += __shfl_xor(a0.w, m, 4);
        a1.x += __shfl_xor(a1.x, m, 4); a1.y += __shfl_xor(a1.y, m, 4);
        a1.z += __shfl_xor(a1.z, m, 4); a1.w += __shfl_xor(a1.w, m, 4);
    }
    float acc[8] = {a0.x, a0.y, a0.z, a0.w, a1.x, a1.y, a1.z, a1.w};
    float d2 = dc * dc;
    const float4* ts = (const float4*)(t + (size_t)node * 8);
    float4 s0 = ts[0], s1 = ts[1];
    float self[8] = {s0.x, s0.y, s0.z, s0.w, s1.x, s1.y, s1.z, s1.w};
    int j0 = q * 2, j1 = q * 2 + 1;
    float* o = out + (size_t)node * NCLS;
    o[j0] = fmaf(d2, self[j0], acc[j0]) + b2[j0];
    if (j1 < NCLS) o[j1] = fmaf(d2, self[j1], acc[j1]) + b2[j1];
}

extern "C" void kernel_launch(void* const* d_in, const int* in_sizes, int n_in,
                              void* d_out, int out_size, void* d_ws, size_t ws_size,
                              hipStream_t stream) {
    const float* x  = (const float*)d_in[0];
    const int*   ei = (const int*)d_in[1];
    const float* W1 = (const float*)d_in[2];
    const float* b1 = (const float*)d_in[3];
    const float* W2 = (const float*)d_in[4];
    const float* b2 = (const float*)d_in[5];
    float* out = (float*)d_out;

    int n = in_sizes[0] / F_IN;   // 100000
    int E = in_sizes[1] / 2;      // 3200000
    int nbkt = (n + NPB - 1) >> BSH;  // 782

    float* ws = (float*)d_ws;
    float* dinv    = ws;                                   // n
    int*   row_ptr = (int*)(ws + n);                       // n+1 (pad 4)
    int*   srcarr  = (int*)(ws + 2 * (size_t)n + 4);       // E
    float* R       = ws + 2 * (size_t)n + 4 + E;           // E floats region
    unsigned* pairs = (unsigned*)R;                        // E (dead after k_bfill)
    float* h1      = R;                                    // 16n (aliases pairs)
    float* t       = R + 16 * (size_t)n;                   // 8n  (aliases pairs)
    int*   bcnt    = (int*)(R + E);                        // 1024*16 (line-padded)
    int*   bptr    = bcnt + 1024 * 16;                     // 1024 dense
    int*   bcur    = bptr + 1024;                          // 1024*16 (line-padded)

    const int B = 256;
    int chunk = (E + GRID_P - 1) / GRID_P;

    k_zero<<<dim3((1024 * 16 + B - 1) / B), dim3(B), 0, stream>>>(bcnt, 1024 * 16);
    k_bhist<<<dim3(GRID_P), dim3(B), 0, stream>>>(ei + E, bcnt, E, nbkt, chunk);
    k_bscan<<<dim3(1), dim3(1024), 0, stream>>>(bcnt, bptr, bcur, nbkt);
    k_part<<<dim3(GRID_P), dim3(B), 0, stream>>>(ei, bcur, pairs, E, nbkt, chunk);
    k_bfill<<<dim3(nbkt), dim3(NPB), 0, stream>>>(pairs, bptr, row_ptr, srcarr, dinv, n, E, nbkt);
    k_gemm1<<<dim3((n + B - 1) / B), dim3(B), 0, stream>>>(x, W1, h1, n);
    k_gather1<<<dim3((n * 4 + B - 1) / B), dim3(B), 0, stream>>>(row_ptr, srcarr, dinv, h1, b1, W2, t, n);
    k_gather2<<<dim3((n * 4 + B - 1) / B), dim3(B), 0, stream>>>(row_ptr, srcarr, dinv, t, b2, out, n);
}

// Round 6
// 519.841 us; speedup vs baseline: 1.7980x; 1.1250x over previous
//
#include <hip/hip_runtime.h>
#include <hip/hip_fp16.h>

#define F_IN 512
#define HID  16
#define NCLS 7
#define BSH  8            // log2(nodes per bucket)
#define NPB  256          // nodes per bucket
#define MAXBKT 1024       // supports n <= 262144
#define GRID_P 512        // blocks for hist/partition passes

// ---------------- bucketed CSR build ----------------

__global__ void k_zero(int* __restrict__ p, int m) {
    int i = blockIdx.x * blockDim.x + threadIdx.x;
    if (i < m) p[i] = 0;
}

__global__ void k_bhist(const int* __restrict__ dst, int* __restrict__ bcnt,
                        int E, int nbkt, int chunk) {
    __shared__ int h[MAXBKT];
    for (int i = threadIdx.x; i < nbkt; i += blockDim.x) h[i] = 0;
    __syncthreads();
    int base = blockIdx.x * chunk;
    int end = min(base + chunk, E);
    for (int e = base + threadIdx.x; e < end; e += blockDim.x)
        atomicAdd(&h[((unsigned)dst[e]) >> BSH], 1);
    __syncthreads();
    for (int i = threadIdx.x; i < nbkt; i += blockDim.x)
        if (h[i]) atomicAdd(&bcnt[i * 16], h[i]);   // stride-16: one counter per line
}

__global__ void k_bscan(const int* __restrict__ bcnt, int* __restrict__ bptr,
                        int* __restrict__ bcur, int nbkt) {
    __shared__ int s[1024];
    int tid = threadIdx.x;
    int v = (tid < nbkt) ? bcnt[tid * 16] : 0;
    s[tid] = v;
    __syncthreads();
    for (int off = 1; off < 1024; off <<= 1) {
        int t = (tid >= off) ? s[tid - off] : 0;
        __syncthreads();
        if (tid >= off) s[tid] += t;
        __syncthreads();
    }
    if (tid < nbkt) {
        int e = s[tid] - v;
        bptr[tid] = e;
        bcur[tid * 16] = e;
    }
}

// partition edges into bucket segments as packed (src<<BSH)|local_dst
__global__ void k_part(const int* __restrict__ ei, int* __restrict__ bcur,
                       unsigned* __restrict__ pairs, int E, int nbkt, int chunk) {
    __shared__ int h[MAXBKT];
    __shared__ int cur[MAXBKT];
    int tid = threadIdx.x;
    for (int i = tid; i < nbkt; i += blockDim.x) h[i] = 0;
    __syncthreads();
    int base = blockIdx.x * chunk;
    int end = min(base + chunk, E);
    for (int e = base + tid; e < end; e += blockDim.x)
        atomicAdd(&h[((unsigned)ei[E + e]) >> BSH], 1);
    __syncthreads();
    for (int i = tid; i < nbkt; i += blockDim.x) {
        int c = h[i];
        cur[i] = c ? atomicAdd(&bcur[i * 16], c) : 0;
    }
    __syncthreads();
    for (int e = base + tid; e < end; e += blockDim.x) {
        int d = ei[E + e];
        int b = ((unsigned)d) >> BSH;
        int pos = atomicAdd(&cur[b], 1);
        pairs[pos] = (((unsigned)ei[e]) << BSH) | (unsigned)(d & (NPB - 1));
    }
}

// per-bucket: LDS hist + scan -> row_ptr, dinv; LDS-cursor fill of srcarr
// (32KB destination window per block -> L2-resident)
__global__ __launch_bounds__(NPB) void k_bfill(
    const unsigned* __restrict__ pairs, const int* __restrict__ bptr,
    int* __restrict__ row_ptr, int* __restrict__ srcarr,
    float* __restrict__ dinv, int n, int E, int nbkt) {
    int b = blockIdx.x, tid = threadIdx.x;
    int pb = bptr[b];
    int pe = (b + 1 < nbkt) ? bptr[b + 1] : E;
    __shared__ int h[NPB];
    __shared__ int s[NPB];
    h[tid] = 0;
    __syncthreads();
    for (int p = pb + tid; p < pe; p += NPB)
        atomicAdd(&h[pairs[p] & (NPB - 1)], 1);
    __syncthreads();
    int cnt = h[tid];
    s[tid] = cnt;
    __syncthreads();
    for (int off = 1; off < NPB; off <<= 1) {
        int t = (tid >= off) ? s[tid - off] : 0;
        __syncthreads();
        if (tid >= off) s[tid] += t;
        __syncthreads();
    }
    int excl = s[tid] - cnt;
    int node = (b << BSH) + tid;
    if (node < n) {
        row_ptr[node] = pb + excl;
        dinv[node] = rsqrtf((float)(cnt + 1));  // +1 self loop
    }
    h[tid] = pb + excl;  // reuse as cursor
    __syncthreads();
    for (int p = pb + tid; p < pe; p += NPB) {
        unsigned v = pairs[p];
        int pos = atomicAdd(&h[v & (NPB - 1)], 1);
        srcarr[pos] = (int)(v >> BSH);
    }
    if (b == 0 && tid == 0) row_ptr[n] = E;
}

// ---------------- layer math ----------------

// h1 = fp16(x @ W1). fp32 compute; 32B fp16 rows (3.2MB total -> fits one
// per-XCD L2 -> gather1 random loads become local-L2 hits).
__global__ __launch_bounds__(256) void k_gemm1(const float* __restrict__ x,
                                               const float* __restrict__ W1,
                                               __half* __restrict__ h1, int n) {
    int node = blockIdx.x * blockDim.x + threadIdx.x;
    if (node >= n) return;
    float acc[HID];
#pragma unroll
    for (int j = 0; j < HID; j++) acc[j] = 0.f;
    const float* xr = x + (size_t)node * F_IN;
    for (int k0 = 0; k0 < F_IN; k0 += 32) {
        float4 xv[8];
        const float4* xp = (const float4*)(xr + k0);
#pragma unroll
        for (int u = 0; u < 8; u++) xv[u] = xp[u];
#pragma unroll
        for (int u = 0; u < 8; u++) {
#pragma unroll
            for (int kk = 0; kk < 4; kk++) {
                float xk = ((const float*)&xv[u])[kk];
                const float* wr = W1 + (size_t)(k0 + u * 4 + kk) * HID;
#pragma unroll
                for (int j = 0; j < HID; j++) acc[j] = fmaf(xk, wr[j], acc[j]);
            }
        }
    }
    __half2 hp[8];
#pragma unroll
    for (int j = 0; j < 8; j++)
        hp[j] = __float22half2_rn(float2{acc[2 * j], acc[2 * j + 1]});
    float4* o4 = (float4*)(h1 + (size_t)node * HID);
    o4[0] = *(float4*)&hp[0];
    o4[1] = *(float4*)&hp[4];
}

__device__ __forceinline__ void acc_row16(const __half* __restrict__ h1, int r,
                                          float nm, float* acc) {
    const float4* hr = (const float4*)(h1 + (size_t)r * HID);
    float4 raw0 = hr[0], raw1 = hr[1];
    const __half2* p0 = (const __half2*)&raw0;
    const __half2* p1 = (const __half2*)&raw1;
#pragma unroll
    for (int j = 0; j < 4; j++) {
        float2 f0 = __half22float2(p0[j]);
        float2 f1 = __half22float2(p1[j]);
        acc[2 * j + 0] = fmaf(nm, f0.x, acc[2 * j + 0]);
        acc[2 * j + 1] = fmaf(nm, f0.y, acc[2 * j + 1]);
        acc[8 + 2 * j + 0] = fmaf(nm, f1.x, acc[8 + 2 * j + 0]);
        acc[8 + 2 * j + 1] = fmaf(nm, f1.y, acc[8 + 2 * j + 1]);
    }
}

// Gather layer 1: 4 lanes/node, lane q takes edges eb+q, eb+q+4, ...; full
// 16-half row per edge (2x16B loads), unroll x2. Butterfly reduce, then
// fused relu + z@W2 -> fp16 t.
__global__ __launch_bounds__(256) void k_gather1(
    const int* __restrict__ row_ptr, const int* __restrict__ srcarr,
    const float* __restrict__ dinv, const __half* __restrict__ h1,
    const float* __restrict__ b1, const float* __restrict__ W2,
    __half* __restrict__ t, int n) {
    int g = blockIdx.x * blockDim.x + threadIdx.x;
    int node = g >> 2, q = g & 3;
    if (node >= n) return;
    int eb = row_ptr[node], ee = row_ptr[node + 1];
    float dc = dinv[node];
    float acc[HID];
#pragma unroll
    for (int j = 0; j < HID; j++) acc[j] = 0.f;
    int e = eb + q;
    for (; e + 4 < ee; e += 8) {
        int r0 = srcarr[e], r1 = srcarr[e + 4];
        float nm0 = dinv[r0] * dc, nm1 = dinv[r1] * dc;
        acc_row16(h1, r0, nm0, acc);
        acc_row16(h1, r1, nm1, acc);
    }
    if (e < ee) {
        int r0 = srcarr[e];
        acc_row16(h1, r0, dinv[r0] * dc, acc);
    }
#pragma unroll
    for (int m = 1; m < 4; m <<= 1)
#pragma unroll
        for (int j = 0; j < HID; j++) acc[j] += __shfl_xor(acc[j], m, 4);
    // self loop + bias + relu (redundant across the 4 lanes)
    float d2 = dc * dc;
    float z[HID];
    {
        const float4* hs4 = (const float4*)(h1 + (size_t)node * HID);
        float4 raw0 = hs4[0], raw1 = hs4[1];
        const __half2* p0 = (const __half2*)&raw0;
        const __half2* p1 = (const __half2*)&raw1;
#pragma unroll
        for (int j = 0; j < 4; j++) {
            float2 f0 = __half22float2(p0[j]);
            float2 f1 = __half22float2(p1[j]);
            z[2 * j + 0] = fmaxf(fmaf(d2, f0.x, acc[2 * j + 0]) + b1[2 * j + 0], 0.f);
            z[2 * j + 1] = fmaxf(fmaf(d2, f0.y, acc[2 * j + 1]) + b1[2 * j + 1], 0.f);
            z[8 + 2 * j + 0] = fmaxf(fmaf(d2, f1.x, acc[8 + 2 * j + 0]) + b1[8 + 2 * j + 0], 0.f);
            z[8 + 2 * j + 1] = fmaxf(fmaf(d2, f1.y, acc[8 + 2 * j + 1]) + b1[8 + 2 * j + 1], 0.f);
        }
    }
    // lane q -> t columns 2q, 2q+1 (col 7 = pad = 0)
    int j0 = q * 2, j1 = q * 2 + 1;
    float t0 = 0.f, t1 = 0.f;
#pragma unroll
    for (int k = 0; k < HID; k++) {
        t0 = fmaf(z[k], W2[k * NCLS + j0], t0);
        if (j1 < NCLS) t1 = fmaf(z[k], W2[k * NCLS + j1], t1);
    }
    if (j1 >= NCLS) t1 = 0.f;
    ((__half2*)t)[(size_t)node * 4 + q] = __float22half2_rn(float2{t0, t1});
}

// Gather layer 2: 8-half rows of t (one 16B load/edge). Lane q writes out
// cols {2q, 2q+1} (col 7 skipped) -> every output element written once.
__global__ __launch_bounds__(256) void k_gather2(
    const int* __restrict__ row_ptr, const int* __restrict__ srcarr,
    const float* __restrict__ dinv, const __half* __restrict__ t,
    const float* __restrict__ b2, float* __restrict__ out, int n) {
    int g = blockIdx.x * blockDim.x + threadIdx.x;
    int node = g >> 2, q = g & 3;
    if (node >= n) return;
    int eb = row_ptr[node], ee = row_ptr[node + 1];
    float dc = dinv[node];
    float acc[8];
#pragma unroll
    for (int j = 0; j < 8; j++) acc[j] = 0.f;
    const float4* t4 = (const float4*)t;
    int e = eb + q;
    for (; e + 4 < ee; e += 8) {
        int r0 = srcarr[e], r1 = srcarr[e + 4];
        float nm0 = dinv[r0] * dc, nm1 = dinv[r1] * dc;
        float4 raw0 = t4[r0], raw1 = t4[r1];
        const __half2* p0 = (const __half2*)&raw0;
        const __half2* p1 = (const __half2*)&raw1;
#pragma unroll
        for (int j = 0; j < 4; j++) {
            float2 f0 = __half22float2(p0[j]);
            float2 f1 = __half22float2(p1[j]);
            acc[2 * j + 0] = fmaf(nm0, f0.x, acc[2 * j + 0]);
            acc[2 * j + 1] = fmaf(nm0, f0.y, acc[2 * j + 1]);
            acc[2 * j + 0] = fmaf(nm1, f1.x, acc[2 * j + 0]);
            acc[2 * j + 1] = fmaf(nm1, f1.y, acc[2 * j + 1]);
        }
    }
    if (e < ee) {
        int r0 = srcarr[e];
        float nm0 = dinv[r0] * dc;
        float4 raw0 = t4[r0];
        const __half2* p0 = (const __half2*)&raw0;
#pragma unroll
        for (int j = 0; j < 4; j++) {
            float2 f0 = __half22float2(p0[j]);
            acc[2 * j + 0] = fmaf(nm0, f0.x, acc[2 * j + 0]);
            acc[2 * j + 1] = fmaf(nm0, f0.y, acc[2 * j + 1]);
        }
    }
#pragma unroll
    for (int m = 1; m < 4; m <<= 1)
#pragma unroll
        for (int j = 0; j < 8; j++) acc[j] += __shfl_xor(acc[j], m, 4);
    float d2 = dc * dc;
    float4 raws = t4[node];
    const __half2* ps = (const __half2*)&raws;
    float self[8];
#pragma unroll
    for (int j = 0; j < 4; j++) {
        float2 f = __half22float2(ps[j]);
        self[2 * j] = f.x;
        self[2 * j + 1] = f.y;
    }
    int j0 = q * 2, j1 = q * 2 + 1;
    float* o = out + (size_t)node * NCLS;
    o[j0] = fmaf(d2, self[j0], acc[j0]) + b2[j0];
    if (j1 < NCLS) o[j1] = fmaf(d2, self[j1], acc[j1]) + b2[j1];
}

extern "C" void kernel_launch(void* const* d_in, const int* in_sizes, int n_in,
                              void* d_out, int out_size, void* d_ws, size_t ws_size,
                              hipStream_t stream) {
    const float* x  = (const float*)d_in[0];
    const int*   ei = (const int*)d_in[1];
    const float* W1 = (const float*)d_in[2];
    const float* b1 = (const float*)d_in[3];
    const float* W2 = (const float*)d_in[4];
    const float* b2 = (const float*)d_in[5];
    float* out = (float*)d_out;

    int n = in_sizes[0] / F_IN;   // 100000
    int E = in_sizes[1] / 2;      // 3200000
    int nbkt = (n + NPB - 1) >> BSH;  // 391

    float* ws = (float*)d_ws;
    float* dinv    = ws;                                   // n
    int*   row_ptr = (int*)(ws + n);                       // n+1 (pad 4)
    int*   srcarr  = (int*)(ws + 2 * (size_t)n + 4);       // E
    float* R       = ws + 2 * (size_t)n + 4 + E;           // E-float region
    unsigned* pairs = (unsigned*)R;                        // E (dead after k_bfill)
    __half* h1     = (__half*)R;                           // 16n halfs (aliases pairs)
    __half* t      = (__half*)(R + 8 * (size_t)n);         // 8n halfs
    int*   bcnt    = (int*)(R + E);                        // 1024*16 (line-padded)
    int*   bptr    = bcnt + 1024 * 16;                     // 1024 dense
    int*   bcur    = bptr + 1024;                          // 1024*16 (line-padded)

    const int B = 256;
    int chunk = (E + GRID_P - 1) / GRID_P;

    k_zero<<<dim3((1024 * 16 + B - 1) / B), dim3(B), 0, stream>>>(bcnt, 1024 * 16);
    k_bhist<<<dim3(GRID_P), dim3(B), 0, stream>>>(ei + E, bcnt, E, nbkt, chunk);
    k_bscan<<<dim3(1), dim3(1024), 0, stream>>>(bcnt, bptr, bcur, nbkt);
    k_part<<<dim3(GRID_P), dim3(B), 0, stream>>>(ei, bcur, pairs, E, nbkt, chunk);
    k_bfill<<<dim3(nbkt), dim3(NPB), 0, stream>>>(pairs, bptr, row_ptr, srcarr, dinv, n, E, nbkt);
    k_gemm1<<<dim3((n + B - 1) / B), dim3(B), 0, stream>>>(x, W1, h1, n);
    k_gather1<<<dim3((n * 4 + B - 1) / B), dim3(B), 0, stream>>>(row_ptr, srcarr, dinv, h1, b1, W2, t, n);
    k_gather2<<<dim3((n * 4 + B - 1) / B), dim3(B), 0, stream>>>(row_ptr, srcarr, dinv, t, b2, out, n);
}